// Round 5
// baseline (45.773 us; speedup 1.0000x reference)
//
#include <hip/hip_runtime.h>
#include <math.h>

// B=8, N=20, H=W=512. loss = sum(bce*valid)/cnt where the last point n with
// exp(-d2/(2*5^2)) > 0.1 (<=> d2 < 50*ln10) defines the per-pixel label.
// Single dispatch, 64 blocks; flag handshake; block 0 wave 0 finalizes.

#define R2_THRESH 115.12925464970229f
#define HW 512
#define NPTS 20
#define ROWS_PER_CHUNK 64
#define NBLOCKS 64               // 8 batches * 8 chunks of 64 rows
#define MAGIC 0x5F3C9A17u

__global__ __launch_bounds__(256)
void pce_one_kernel(const float* __restrict__ y_pred,
                    const int* __restrict__ point_labels,
                    const float* __restrict__ point_coords,
                    float* __restrict__ ws,        // [128] S/C pairs
                    unsigned* __restrict__ flags,  // [64]; !=MAGIC on entry, 0 on exit
                    float* __restrict__ out) {
    const int b     = blockIdx.x >> 3;
    const int chunk = blockIdx.x & 7;
    const int y0    = chunk * ROWS_PER_CHUNK;
    const int tid   = threadIdx.x;
    const int r8    = tid >> 5;               // 8 row-groups, 32 lanes each
    const int lane  = tid & 31;

    __shared__ float s_xc[ROWS_PER_CHUNK][NPTS];
    __shared__ float s_lim[ROWS_PER_CHUNK][NPTS];
    __shared__ float s_lab[ROWS_PER_CHUNK][NPTS];
    __shared__ int   s_x0[ROWS_PER_CHUNK], s_x1[ROWS_PER_CHUNK];

    // per-batch point data into registers (lane<NPTS)
    float yc = 0.0f, xc = 0.0f, lab = 0.0f;
    if (lane < NPTS) {
        yc  = point_coords[b * (NPTS * 2) + lane * 2 + 0] * (float)HW;
        xc  = point_coords[b * (NPTS * 2) + lane * 2 + 1] * (float)HW;
        lab = (float)point_labels[b * NPTS + lane];
    }

    // ---- setup all 64 rows (disjoint LDS slots; zero syncs inside) ----
    #pragma unroll
    for (int g = 0; g < 8; ++g) {
        const int row = g * 8 + r8;
        float xlo = INFINITY, xhi = -INFINITY;
        if (lane < NPTS) {
            float dy  = (float)(y0 + row) - yc;
            float lim = R2_THRESH - dy * dy;   // lim<=0 -> dx*dx<lim never true
            s_xc[row][lane]  = xc;
            s_lim[row][lane] = lim;
            s_lab[row][lane] = lab;
            if (lim > 0.0f) {
                float s = sqrtf(lim);
                xlo = xc - s;
                xhi = xc + s;
            }
        }
        #pragma unroll
        for (int off = 16; off > 0; off >>= 1) {
            xlo = fminf(xlo, __shfl_xor(xlo, off, 32));
            xhi = fmaxf(xhi, __shfl_xor(xhi, off, 32));
        }
        if (lane == 0) {
            s_x0[row] = (int)fminf(fmaxf(floorf(xlo), 0.0f), 512.0f);
            s_x1[row] = (int)fminf(fmaxf(ceilf(xhi), -1.0f), 511.0f); // empty -> x0>x1
        }
    }
    __syncthreads();

    // ---- pixel phase: row-group r8 covers rows r8, r8+8, ... within bbox ----
    float sum = 0.0f, cnt = 0.0f;
    const float* base = y_pred + (size_t)b * HW * HW;
    for (int g = 0; g < 8; ++g) {
        const int row = g * 8 + r8;
        const int x0 = s_x0[row], x1 = s_x1[row];
        const float* rp = base + (size_t)(y0 + row) * HW;
        for (int px = x0 + lane; px <= x1; px += 32) {
            const float fx = (float)px;
            float pl = 0.0f;
            bool  valid = false;
            #pragma unroll
            for (int k = 0; k < NPTS; ++k) {
                float dx = fx - s_xc[row][k];
                if (dx * dx < s_lim[row][k]) { pl = s_lab[row][k]; valid = true; } // last k wins
            }
            if (valid) {
                float l   = rp[px];
                float bce = fmaxf(l, 0.0f) - l * pl + log1pf(expf(-fabsf(l)));
                sum += bce;
                cnt += 1.0f;
            }
        }
    }

    // ---- block reduction: wave shuffle then 4-wave LDS combine ----
    #pragma unroll
    for (int off = 32; off > 0; off >>= 1) {
        sum += __shfl_down(sum, off, 64);
        cnt += __shfl_down(cnt, off, 64);
    }
    __shared__ float rs[4], rc[4];
    if ((tid & 63) == 0) { rs[tid >> 6] = sum; rc[tid >> 6] = cnt; }
    __syncthreads();
    if (tid == 0) {
        float S = rs[0] + rs[1] + rs[2] + rs[3];
        float C = rc[0] + rc[1] + rc[2] + rc[3];
        __hip_atomic_store(&ws[blockIdx.x * 2 + 0], S, __ATOMIC_RELAXED, __HIP_MEMORY_SCOPE_AGENT);
        __hip_atomic_store(&ws[blockIdx.x * 2 + 1], C, __ATOMIC_RELAXED, __HIP_MEMORY_SCOPE_AGENT);
        if (blockIdx.x != 0)
            __hip_atomic_store(&flags[blockIdx.x], MAGIC, __ATOMIC_RELEASE, __HIP_MEMORY_SCOPE_AGENT);
    }
    if (blockIdx.x != 0) return;

    // ---- block 0, wave 0: spin on 63 flags (one per lane), then finalize ----
    if (tid < 64) {
        if (tid >= 1) {
            unsigned f = 0;
            while (f != MAGIC)
                f = __hip_atomic_load(&flags[tid], __ATOMIC_ACQUIRE, __HIP_MEMORY_SCOPE_AGENT);
        }
        // lane t reads block t's partial (guarded by flags[t]; t=0 is our own)
        float S = __hip_atomic_load(&ws[tid * 2 + 0], __ATOMIC_RELAXED, __HIP_MEMORY_SCOPE_AGENT);
        float C = __hip_atomic_load(&ws[tid * 2 + 1], __ATOMIC_RELAXED, __HIP_MEMORY_SCOPE_AGENT);
        #pragma unroll
        for (int off = 32; off > 0; off >>= 1) {
            S += __shfl_down(S, off, 64);
            C += __shfl_down(C, off, 64);
        }
        if (tid == 0) out[0] = (C > 0.0f) ? (S / C) : 0.0f;
        // clear my flag for the next replay (ws fully rewritten before flags re-set)
        __hip_atomic_store(&flags[tid], 0u, __ATOMIC_RELAXED, __HIP_MEMORY_SCOPE_AGENT);
    }
}

extern "C" void kernel_launch(void* const* d_in, const int* in_sizes, int n_in,
                              void* d_out, int out_size, void* d_ws, size_t ws_size,
                              hipStream_t stream) {
    const float* y_pred       = (const float*)d_in[0];   // (8,1,512,512) f32
    const int*   point_labels = (const int*)d_in[1];     // (8,20) i32
    const float* point_coords = (const float*)d_in[2];   // (8,20,2) f32
    float*       out          = (float*)d_out;           // scalar f32
    float*       ws           = (float*)d_ws;            // 128 floats partials
    unsigned*    flags        = (unsigned*)((float*)d_ws + 128);  // 64 u32

    pce_one_kernel<<<NBLOCKS, 256, 0, stream>>>(y_pred, point_labels, point_coords,
                                                ws, flags, out);
}

// Round 6
// 27.215 us; speedup vs baseline: 1.6819x; 1.6819x over previous
//
#include <hip/hip_runtime.h>
#include <math.h>

// B=8, N=20, H=W=512. loss = sum(bce*valid)/cnt where the last point n with
// exp(-d2/(2*5^2)) > 0.1 (<=> d2 < 50*ln10) defines the per-pixel label.
// Single main dispatch; "last block finalizes" via hierarchical done-counters
// (no polling). Counters zeroed by a 64B memset node each call.

#define R2_THRESH 115.12925464970229f
#define HW 512
#define NPTS 20
#define NBLOCKS 512              // 8 batches * 64 chunks of 8 rows

__global__ __launch_bounds__(256)
void pce_kernel(const float* __restrict__ y_pred,
                const int* __restrict__ point_labels,
                const float* __restrict__ point_coords,
                unsigned* __restrict__ ctr,     // [9]: grp[8] @0..7, glob @8 (zeroed per call)
                float* __restrict__ slots,      // [1024]: per-block {S,C}
                float* __restrict__ out) {
    const int b     = blockIdx.x >> 6;
    const int chunk = blockIdx.x & 63;
    const int y0    = chunk * 8;
    const int tid   = threadIdx.x;
    const int r     = tid >> 5;               // 8 rows, 32 lanes each
    const int lane  = tid & 31;

    __shared__ float s_xc[8][NPTS], s_lim[8][NPTS], s_lab[8][NPTS];

    // ---- parallel setup: thread (r, n=lane<20) tests point n on row y0+r ----
    float xlo = INFINITY, xhi = -INFINITY;
    if (lane < NPTS) {
        float2 cc = ((const float2*)point_coords)[b * NPTS + lane];
        float yc  = cc.x * (float)HW;
        float xc  = cc.y * (float)HW;
        float dy  = (float)(y0 + r) - yc;
        float lim = R2_THRESH - dy * dy;      // lim<=0 -> dx*dx<lim never true
        s_xc[r][lane]  = xc;
        s_lim[r][lane] = lim;
        s_lab[r][lane] = (float)point_labels[b * NPTS + lane];
        if (lim > 0.0f) {
            float s = sqrtf(lim);
            xlo = xc - s;
            xhi = xc + s;
        }
    }
    #pragma unroll
    for (int off = 16; off > 0; off >>= 1) {
        xlo = fminf(xlo, __shfl_xor(xlo, off, 32));
        xhi = fmaxf(xhi, __shfl_xor(xhi, off, 32));
    }
    const int x0 = (int)fminf(fmaxf(floorf(xlo), 0.0f), 512.0f);
    const int x1 = (int)fminf(fmaxf(ceilf(xhi), -1.0f), 511.0f);   // empty -> x0 > x1
    __syncthreads();

    // ---- pixel loop: 32 lanes cover this row's bbox; load hoisted early ----
    float sum = 0.0f, cnt = 0.0f;
    const float* row = y_pred + (size_t)b * HW * HW + (size_t)(y0 + r) * HW;
    for (int px = x0 + lane; px <= x1; px += 32) {
        float l = row[px];                    // unconditional: overlaps with test below
        const float fx = (float)px;
        float lab = 0.0f;
        bool  valid = false;
        #pragma unroll
        for (int k = 0; k < NPTS; ++k) {
            float dx = fx - s_xc[r][k];
            if (dx * dx < s_lim[r][k]) { lab = s_lab[r][k]; valid = true; }  // last k wins
        }
        if (valid) {
            sum += fmaxf(l, 0.0f) - l * lab + log1pf(expf(-fabsf(l)));
            cnt += 1.0f;
        }
    }

    // ---- block reduction ----
    #pragma unroll
    for (int off = 32; off > 0; off >>= 1) {
        sum += __shfl_down(sum, off, 64);
        cnt += __shfl_down(cnt, off, 64);
    }
    __shared__ float rs[4], rc[4];
    __shared__ int s_fin;
    if ((tid & 63) == 0) { rs[tid >> 6] = sum; rc[tid >> 6] = cnt; }
    __syncthreads();
    if (tid == 0) {
        float S = rs[0] + rs[1] + rs[2] + rs[3];
        float C = rc[0] + rc[1] + rc[2] + rc[3];
        slots[blockIdx.x * 2 + 0] = S;
        slots[blockIdx.x * 2 + 1] = C;
        __threadfence();                       // flush slot to coherence point
        int fin = 0;
        unsigned old = atomicAdd(&ctr[blockIdx.x & 7], 1u);   // 64 blocks per group
        if (old == 63u) {                      // group-last
            __threadfence();
            unsigned old2 = atomicAdd(&ctr[8], 1u);           // 8 groups
            if (old2 == 7u) fin = 1;           // globally last -> finalize
        }
        s_fin = fin;
    }
    __syncthreads();
    if (!s_fin) return;

    // ---- finalizer block: fixed-order reduction of 512 slots ----
    __threadfence();                           // invalidate stale cached lines
    float S, C;
    {
        float s0 = __hip_atomic_load(&slots[tid * 2 + 0],         __ATOMIC_RELAXED, __HIP_MEMORY_SCOPE_AGENT);
        float c0 = __hip_atomic_load(&slots[tid * 2 + 1],         __ATOMIC_RELAXED, __HIP_MEMORY_SCOPE_AGENT);
        float s1 = __hip_atomic_load(&slots[(tid + 256) * 2 + 0], __ATOMIC_RELAXED, __HIP_MEMORY_SCOPE_AGENT);
        float c1 = __hip_atomic_load(&slots[(tid + 256) * 2 + 1], __ATOMIC_RELAXED, __HIP_MEMORY_SCOPE_AGENT);
        S = s0 + s1;
        C = c0 + c1;
    }
    #pragma unroll
    for (int off = 32; off > 0; off >>= 1) {
        S += __shfl_down(S, off, 64);
        C += __shfl_down(C, off, 64);
    }
    if ((tid & 63) == 0) { rs[tid >> 6] = S; rc[tid >> 6] = C; }
    __syncthreads();
    if (tid == 0) {
        float SS = rs[0] + rs[1] + rs[2] + rs[3];
        float CC = rc[0] + rc[1] + rc[2] + rc[3];
        out[0] = (CC > 0.0f) ? (SS / CC) : 0.0f;
    }
}

extern "C" void kernel_launch(void* const* d_in, const int* in_sizes, int n_in,
                              void* d_out, int out_size, void* d_ws, size_t ws_size,
                              hipStream_t stream) {
    const float* y_pred       = (const float*)d_in[0];   // (8,1,512,512) f32
    const int*   point_labels = (const int*)d_in[1];     // (8,20) i32
    const float* point_coords = (const float*)d_in[2];   // (8,20,2) f32
    float*       out          = (float*)d_out;           // scalar f32

    unsigned* ctr   = (unsigned*)d_ws;                   // 9 u32 in first 64 B
    float*    slots = (float*)((char*)d_ws + 256);       // 1024 floats

    hipMemsetAsync(d_ws, 0, 64, stream);                 // zero counters each call
    pce_kernel<<<NBLOCKS, 256, 0, stream>>>(y_pred, point_labels, point_coords,
                                            ctr, slots, out);
}

// Round 7
// 21.553 us; speedup vs baseline: 2.1238x; 1.2627x over previous
//
#include <hip/hip_runtime.h>
#include <math.h>

// B=8, N=20, H=W=512. loss = sum(bce*valid)/cnt where the last point n with
// exp(-d2/(2*5^2)) > 0.1 (<=> d2 < 50*ln10) defines the per-pixel label.
// Single dispatch. Hierarchical XCD-aware handshake:
//   worker block i -> flag[i];  leader g (blocks 0..7) polls blocks ≡ g (mod 8)
//   (same XCD under round-robin dispatch), posts group partial + gflag;
//   block 0 polls 7 gflags and finalizes. All polls s_sleep-backed.

#define R2_THRESH 115.12925464970229f
#define HW 512
#define NPTS 20
#define NBLOCKS 512
#define NGRP 8
#define GSIZE 64
#define MAGIC 0x5F3C9A17u

__global__ __launch_bounds__(256)
void pce_kernel(const float* __restrict__ y_pred,
                const int* __restrict__ point_labels,
                const float* __restrict__ point_coords,
                float* __restrict__ slots,      // [1024] per-block {S,C}
                unsigned* __restrict__ flags,   // [512]; != MAGIC on entry, cleared on exit
                float* __restrict__ gslots,     // [16] per-group {S,C}
                unsigned* __restrict__ gflags,  // [8];   != MAGIC on entry, cleared on exit
                float* __restrict__ out) {
    const int bid   = blockIdx.x;
    const int b     = bid >> 6;
    const int chunk = bid & 63;
    const int y0    = chunk * 8;
    const int tid   = threadIdx.x;
    const int r     = tid >> 5;               // 8 rows, 32 lanes each
    const int lane  = tid & 31;

    __shared__ float s_xc[8][NPTS], s_lim[8][NPTS], s_lab[8][NPTS];

    // ---- parallel setup ----
    float xlo = INFINITY, xhi = -INFINITY;
    if (lane < NPTS) {
        float2 cc = ((const float2*)point_coords)[b * NPTS + lane];
        float yc  = cc.x * (float)HW;
        float xc  = cc.y * (float)HW;
        float dy  = (float)(y0 + r) - yc;
        float lim = R2_THRESH - dy * dy;      // lim<=0 -> dx*dx<lim never true
        s_xc[r][lane]  = xc;
        s_lim[r][lane] = lim;
        s_lab[r][lane] = (float)point_labels[b * NPTS + lane];
        if (lim > 0.0f) {
            float s = sqrtf(lim);
            xlo = xc - s;
            xhi = xc + s;
        }
    }
    #pragma unroll
    for (int off = 16; off > 0; off >>= 1) {
        xlo = fminf(xlo, __shfl_xor(xlo, off, 32));
        xhi = fmaxf(xhi, __shfl_xor(xhi, off, 32));
    }
    const int x0 = (int)fminf(fmaxf(floorf(xlo), 0.0f), 512.0f);
    const int x1 = (int)fminf(fmaxf(ceilf(xhi), -1.0f), 511.0f);   // empty -> x0 > x1
    __syncthreads();

    // ---- pixel loop ----
    float sum = 0.0f, cnt = 0.0f;
    const float* row = y_pred + (size_t)b * HW * HW + (size_t)(y0 + r) * HW;
    for (int px = x0 + lane; px <= x1; px += 32) {
        float l = row[px];                    // hoisted: overlaps with tests below
        const float fx = (float)px;
        float lab = 0.0f;
        bool  valid = false;
        #pragma unroll
        for (int k = 0; k < NPTS; ++k) {
            float dx = fx - s_xc[r][k];
            if (dx * dx < s_lim[r][k]) { lab = s_lab[r][k]; valid = true; }  // last k wins
        }
        if (valid) {
            sum += fmaxf(l, 0.0f) - l * lab + log1pf(expf(-fabsf(l)));
            cnt += 1.0f;
        }
    }

    // ---- block reduction ----
    #pragma unroll
    for (int off = 32; off > 0; off >>= 1) {
        sum += __shfl_down(sum, off, 64);
        cnt += __shfl_down(cnt, off, 64);
    }
    __shared__ float rs[4], rc[4];
    if ((tid & 63) == 0) { rs[tid >> 6] = sum; rc[tid >> 6] = cnt; }
    __syncthreads();
    if (tid == 0) {
        float S = rs[0] + rs[1] + rs[2] + rs[3];
        float C = rc[0] + rc[1] + rc[2] + rc[3];
        __hip_atomic_store(&slots[bid * 2 + 0], S, __ATOMIC_RELAXED, __HIP_MEMORY_SCOPE_AGENT);
        __hip_atomic_store(&slots[bid * 2 + 1], C, __ATOMIC_RELAXED, __HIP_MEMORY_SCOPE_AGENT);
        __hip_atomic_store(&flags[bid], MAGIC, __ATOMIC_RELEASE, __HIP_MEMORY_SCOPE_AGENT);
    }
    if (bid >= NGRP || tid >= 64) return;     // only wave 0 of blocks 0..7 continue

    const int g = bid;

    // ---- level 1: leader g polls its 64 members (blocks ≡ g mod 8) ----
    const int member = g + NGRP * tid;        // tid in [0,64)
    {
        unsigned f = 0;
        do {
            f = __hip_atomic_load(&flags[member], __ATOMIC_ACQUIRE, __HIP_MEMORY_SCOPE_AGENT);
            if (f != MAGIC) __builtin_amdgcn_s_sleep(1);
        } while (f != MAGIC);
    }
    float S = __hip_atomic_load(&slots[member * 2 + 0], __ATOMIC_RELAXED, __HIP_MEMORY_SCOPE_AGENT);
    float C = __hip_atomic_load(&slots[member * 2 + 1], __ATOMIC_RELAXED, __HIP_MEMORY_SCOPE_AGENT);
    #pragma unroll
    for (int off = 32; off > 0; off >>= 1) {
        S += __shfl_down(S, off, 64);
        C += __shfl_down(C, off, 64);
    }
    // clear my member's flag (my read already completed; only this lane reads it)
    __hip_atomic_store(&flags[member], 0u, __ATOMIC_RELAXED, __HIP_MEMORY_SCOPE_AGENT);

    if (g != 0) {
        if (tid == 0) {
            __hip_atomic_store(&gslots[g * 2 + 0], S, __ATOMIC_RELAXED, __HIP_MEMORY_SCOPE_AGENT);
            __hip_atomic_store(&gslots[g * 2 + 1], C, __ATOMIC_RELAXED, __HIP_MEMORY_SCOPE_AGENT);
            __hip_atomic_store(&gflags[g], MAGIC, __ATOMIC_RELEASE, __HIP_MEMORY_SCOPE_AGENT);
        }
        return;
    }

    // ---- level 2: block 0 polls 7 group flags and finalizes ----
    float S2 = 0.0f, C2 = 0.0f;
    if (tid == 0) { S2 = S; C2 = C; }         // group 0 stays in-register
    if (tid >= 1 && tid < NGRP) {
        unsigned f = 0;
        do {
            f = __hip_atomic_load(&gflags[tid], __ATOMIC_ACQUIRE, __HIP_MEMORY_SCOPE_AGENT);
            if (f != MAGIC) __builtin_amdgcn_s_sleep(1);
        } while (f != MAGIC);
        S2 = __hip_atomic_load(&gslots[tid * 2 + 0], __ATOMIC_RELAXED, __HIP_MEMORY_SCOPE_AGENT);
        C2 = __hip_atomic_load(&gslots[tid * 2 + 1], __ATOMIC_RELAXED, __HIP_MEMORY_SCOPE_AGENT);
    }
    #pragma unroll
    for (int off = 4; off > 0; off >>= 1) {   // reduce lanes 0..7
        S2 += __shfl_down(S2, off, 8);
        C2 += __shfl_down(C2, off, 8);
    }
    if (tid == 0) out[0] = (C2 > 0.0f) ? (S2 / C2) : 0.0f;
    if (tid >= 1 && tid < NGRP)               // clear after my read completed
        __hip_atomic_store(&gflags[tid], 0u, __ATOMIC_RELAXED, __HIP_MEMORY_SCOPE_AGENT);
}

extern "C" void kernel_launch(void* const* d_in, const int* in_sizes, int n_in,
                              void* d_out, int out_size, void* d_ws, size_t ws_size,
                              hipStream_t stream) {
    const float* y_pred       = (const float*)d_in[0];   // (8,1,512,512) f32
    const int*   point_labels = (const int*)d_in[1];     // (8,20) i32
    const float* point_coords = (const float*)d_in[2];   // (8,20,2) f32
    float*       out          = (float*)d_out;           // scalar f32

    char* w = (char*)d_ws;
    float*    slots  = (float*)(w);             // 1024 f32 @ 0
    unsigned* flags  = (unsigned*)(w + 4096);   // 512 u32
    float*    gslots = (float*)(w + 6144);      // 16 f32
    unsigned* gflags = (unsigned*)(w + 6272);   // 8 u32 (own line)

    pce_kernel<<<NBLOCKS, 256, 0, stream>>>(y_pred, point_labels, point_coords,
                                            slots, flags, gslots, gflags, out);
}

// Round 8
// 19.622 us; speedup vs baseline: 2.3328x; 1.0984x over previous
//
#include <hip/hip_runtime.h>
#include <math.h>

// B=8, N=20, H=W=512. loss = sum(bce*valid)/cnt where the last point n with
// exp(-d2/(2*5^2)) > 0.1 (<=> d2 < 50*ln10) defines the per-pixel label.
// Single dispatch; flat flag handshake (R4 structure, best=21.06us) with
// paired 8-byte flag polling and micro-optimized worker body.

#define R2_THRESH 115.12925464970229f
#define HW 512
#define NPTS 20
#define NBLOCKS 512
#define MAGIC 0x5F3C9A17u
#define MAGIC2 0x5F3C9A175F3C9A17ull

__global__ __launch_bounds__(256)
void pce_kernel(const float* __restrict__ y_pred,
                const int* __restrict__ point_labels,
                const float* __restrict__ point_coords,
                float* __restrict__ slots,      // [1024] per-block {S,C}
                unsigned* __restrict__ flags,   // [512]; != MAGIC on entry, cleared on exit
                float* __restrict__ out) {
    const int bid   = blockIdx.x;
    const int b     = bid >> 6;
    const int chunk = bid & 63;
    const int y0    = chunk * 8;
    const int tid   = threadIdx.x;
    const int r     = tid >> 5;               // 8 rows, 32 lanes each
    const int lane  = tid & 31;

    __shared__ float s_xc[8][NPTS], s_lim[8][NPTS], s_lab[8][NPTS];

    // ---- parallel setup: thread (r, n=lane<20) tests point n on row y0+r ----
    float xlo = INFINITY, xhi = -INFINITY;
    if (lane < NPTS) {
        float2 cc = ((const float2*)point_coords)[b * NPTS + lane];
        float yc  = cc.x * (float)HW;
        float xc  = cc.y * (float)HW;
        float dy  = (float)(y0 + r) - yc;
        float lim = R2_THRESH - dy * dy;      // lim<=0 -> dx*dx<lim never true
        s_xc[r][lane]  = xc;
        s_lim[r][lane] = lim;
        s_lab[r][lane] = (float)point_labels[b * NPTS + lane];
        if (lim > 0.0f) {
            float s = sqrtf(lim);
            xlo = xc - s;
            xhi = xc + s;
        }
    }
    #pragma unroll
    for (int off = 16; off > 0; off >>= 1) {
        xlo = fminf(xlo, __shfl_xor(xlo, off, 32));
        xhi = fmaxf(xhi, __shfl_xor(xhi, off, 32));
    }
    const int x0 = (int)fminf(fmaxf(floorf(xlo), 0.0f), 512.0f);
    const int x1 = (int)fminf(fmaxf(ceilf(xhi), -1.0f), 511.0f);   // empty -> x0 > x1
    __syncthreads();

    // ---- pixel loop: 32 lanes cover this row's bbox; load hoisted early ----
    float sum = 0.0f, cnt = 0.0f;
    const float* row = y_pred + (size_t)b * HW * HW + (size_t)(y0 + r) * HW;
    for (int px = x0 + lane; px <= x1; px += 32) {
        float l = row[px];                    // unconditional: overlaps with tests below
        const float fx = (float)px;
        float lab = 0.0f;
        bool  valid = false;
        #pragma unroll
        for (int k = 0; k < NPTS; ++k) {
            float dx = fx - s_xc[r][k];
            if (dx * dx < s_lim[r][k]) { lab = s_lab[r][k]; valid = true; }  // last k wins
        }
        if (valid) {
            sum += fmaxf(l, 0.0f) - l * lab + log1pf(expf(-fabsf(l)));
            cnt += 1.0f;
        }
    }

    // ---- block reduction ----
    #pragma unroll
    for (int off = 32; off > 0; off >>= 1) {
        sum += __shfl_down(sum, off, 64);
        cnt += __shfl_down(cnt, off, 64);
    }
    __shared__ float rs[4], rc[4];
    if ((tid & 63) == 0) { rs[tid >> 6] = sum; rc[tid >> 6] = cnt; }
    __syncthreads();
    if (tid == 0) {
        float S = rs[0] + rs[1] + rs[2] + rs[3];
        float C = rc[0] + rc[1] + rc[2] + rc[3];
        __hip_atomic_store(&slots[bid * 2 + 0], S, __ATOMIC_RELAXED, __HIP_MEMORY_SCOPE_AGENT);
        __hip_atomic_store(&slots[bid * 2 + 1], C, __ATOMIC_RELAXED, __HIP_MEMORY_SCOPE_AGENT);
        __hip_atomic_store(&flags[bid], MAGIC, __ATOMIC_RELEASE, __HIP_MEMORY_SCOPE_AGENT);
    }
    if (bid != 0) return;

    // ---- block 0: thread t polls blocks {2t, 2t+1} as one 8-byte acquire load ----
    {
        unsigned long long f = 0;
        unsigned long long* fp = (unsigned long long*)&flags[2 * tid];  // 8B-aligned
        do {
            f = __hip_atomic_load(fp, __ATOMIC_ACQUIRE, __HIP_MEMORY_SCOPE_AGENT);
            if (f != MAGIC2) __builtin_amdgcn_s_sleep(1);
        } while (f != MAGIC2);
    }

    // ---- finalize: fixed-order reduction of 512 slots (thread t owns 2t,2t+1) ----
    {
        float s0 = __hip_atomic_load(&slots[4 * tid + 0], __ATOMIC_RELAXED, __HIP_MEMORY_SCOPE_AGENT);
        float c0 = __hip_atomic_load(&slots[4 * tid + 1], __ATOMIC_RELAXED, __HIP_MEMORY_SCOPE_AGENT);
        float s1 = __hip_atomic_load(&slots[4 * tid + 2], __ATOMIC_RELAXED, __HIP_MEMORY_SCOPE_AGENT);
        float c1 = __hip_atomic_load(&slots[4 * tid + 3], __ATOMIC_RELAXED, __HIP_MEMORY_SCOPE_AGENT);
        float S = s0 + s1;
        float C = c0 + c1;
        #pragma unroll
        for (int off = 32; off > 0; off >>= 1) {
            S += __shfl_down(S, off, 64);
            C += __shfl_down(C, off, 64);
        }
        if ((tid & 63) == 0) { rs[tid >> 6] = S; rc[tid >> 6] = C; }
        __syncthreads();
        if (tid == 0) {
            float SS = rs[0] + rs[1] + rs[2] + rs[3];
            float CC = rc[0] + rc[1] + rc[2] + rc[3];
            out[0] = (CC > 0.0f) ? (SS / CC) : 0.0f;
        }
        // clear my two flags for the next replay (my reads are done)
        __hip_atomic_store(&flags[2 * tid + 0], 0u, __ATOMIC_RELAXED, __HIP_MEMORY_SCOPE_AGENT);
        __hip_atomic_store(&flags[2 * tid + 1], 0u, __ATOMIC_RELAXED, __HIP_MEMORY_SCOPE_AGENT);
    }
}

extern "C" void kernel_launch(void* const* d_in, const int* in_sizes, int n_in,
                              void* d_out, int out_size, void* d_ws, size_t ws_size,
                              hipStream_t stream) {
    const float* y_pred       = (const float*)d_in[0];   // (8,1,512,512) f32
    const int*   point_labels = (const int*)d_in[1];     // (8,20) i32
    const float* point_coords = (const float*)d_in[2];   // (8,20,2) f32
    float*       out          = (float*)d_out;           // scalar f32

    char* w = (char*)d_ws;
    float*    slots = (float*)(w);              // 1024 f32
    unsigned* flags = (unsigned*)(w + 4096);    // 512 u32 (8B-aligned)

    pce_kernel<<<NBLOCKS, 256, 0, stream>>>(y_pred, point_labels, point_coords,
                                            slots, flags, out);
}

// Round 9
// 19.564 us; speedup vs baseline: 2.3396x; 1.0029x over previous
//
#include <hip/hip_runtime.h>
#include <math.h>

// B=8, N=20, H=W=512. loss = sum(bce*valid)/cnt where the last point n with
// exp(-d2/(2*5^2)) > 0.1 (<=> d2 < 50*ln10) defines the per-pixel label.
// Single dispatch; flat paired-flag handshake (R8, 19.6us) + unconditional
// strip preload to LDS (kills the coords->bbox->load serial chain) + packed
// 8B {S,C} slots.

#define R2_THRESH 115.12925464970229f
#define HW 512
#define NPTS 20
#define NBLOCKS 512
#define MAGIC 0x5F3C9A17u
#define MAGIC2 0x5F3C9A175F3C9A17ull

__global__ __launch_bounds__(256)
void pce_kernel(const float* __restrict__ y_pred,
                const int* __restrict__ point_labels,
                const float* __restrict__ point_coords,
                unsigned long long* __restrict__ slots, // [512] packed {C:hi32,S:lo32}
                unsigned* __restrict__ flags,           // [512]; != MAGIC on entry, cleared on exit
                float* __restrict__ out) {
    const int bid  = blockIdx.x;
    const int b    = bid >> 6;
    const int y0   = (bid & 63) * 8;
    const int tid  = threadIdx.x;
    const int r    = tid >> 5;               // 8 rows, 32 lanes each
    const int lane = tid & 31;

    __shared__ float s_strip[8][HW];         // 16 KB
    __shared__ float s_xc[8][NPTS], s_lim[8][NPTS], s_lab[8][NPTS];

    // ---- issue strip loads FIRST (independent of coords; col = lane*4 + j*128) ----
    const float4* grow = (const float4*)(y_pred + (size_t)b * HW * HW + (size_t)(y0 + r) * HW);
    float4 v0 = grow[lane];
    float4 v1 = grow[lane + 32];
    float4 v2 = grow[lane + 64];
    float4 v3 = grow[lane + 96];

    // ---- coords / point tables / bbox (overlaps the strip loads) ----
    float xlo = INFINITY, xhi = -INFINITY;
    if (lane < NPTS) {
        float2 cc = ((const float2*)point_coords)[b * NPTS + lane];
        float yc  = cc.x * (float)HW;
        float xc  = cc.y * (float)HW;
        float dy  = (float)(y0 + r) - yc;
        float lim = R2_THRESH - dy * dy;      // lim<=0 -> dx*dx<lim never true
        s_xc[r][lane]  = xc;
        s_lim[r][lane] = lim;
        s_lab[r][lane] = (float)point_labels[b * NPTS + lane];
        if (lim > 0.0f) {
            float s = sqrtf(lim);
            xlo = xc - s;
            xhi = xc + s;
        }
    }
    #pragma unroll
    for (int off = 16; off > 0; off >>= 1) {
        xlo = fminf(xlo, __shfl_xor(xlo, off, 32));
        xhi = fmaxf(xhi, __shfl_xor(xhi, off, 32));
    }
    const int x0 = (int)fminf(fmaxf(floorf(xlo), 0.0f), 512.0f);
    const int x1 = (int)fminf(fmaxf(ceilf(xhi), -1.0f), 511.0f);   // empty -> x0 > x1

    // ---- strip -> LDS (4-way bank aliasing only) ----
    {
        float4* dst = (float4*)&s_strip[r][0];
        dst[lane]      = v0;
        dst[lane + 32] = v1;
        dst[lane + 64] = v2;
        dst[lane + 96] = v3;
    }
    __syncthreads();

    // ---- pixel loop: reads hit LDS, no global latency on this path ----
    float sum = 0.0f, cnt = 0.0f;
    for (int px = x0 + lane; px <= x1; px += 32) {
        float l = s_strip[r][px];
        const float fx = (float)px;
        float lab = 0.0f;
        bool  valid = false;
        #pragma unroll
        for (int k = 0; k < NPTS; ++k) {
            float dx = fx - s_xc[r][k];
            if (dx * dx < s_lim[r][k]) { lab = s_lab[r][k]; valid = true; }  // last k wins
        }
        if (valid) {
            sum += fmaxf(l, 0.0f) - l * lab + log1pf(expf(-fabsf(l)));
            cnt += 1.0f;
        }
    }

    // ---- block reduction ----
    #pragma unroll
    for (int off = 32; off > 0; off >>= 1) {
        sum += __shfl_down(sum, off, 64);
        cnt += __shfl_down(cnt, off, 64);
    }
    __shared__ float rs[4], rc[4];
    if ((tid & 63) == 0) { rs[tid >> 6] = sum; rc[tid >> 6] = cnt; }
    __syncthreads();
    if (tid == 0) {
        float S = rs[0] + rs[1] + rs[2] + rs[3];
        float C = rc[0] + rc[1] + rc[2] + rc[3];
        unsigned long long w = ((unsigned long long)__float_as_uint(C) << 32)
                             | (unsigned long long)__float_as_uint(S);
        __hip_atomic_store(&slots[bid], w, __ATOMIC_RELAXED, __HIP_MEMORY_SCOPE_AGENT);
        __hip_atomic_store(&flags[bid], MAGIC, __ATOMIC_RELEASE, __HIP_MEMORY_SCOPE_AGENT);
    }
    if (bid != 0) return;

    // ---- block 0: thread t polls blocks {2t,2t+1} as one 8B acquire load ----
    {
        unsigned long long f = 0;
        unsigned long long* fp = (unsigned long long*)&flags[2 * tid];
        do {
            f = __hip_atomic_load(fp, __ATOMIC_ACQUIRE, __HIP_MEMORY_SCOPE_AGENT);
            if (f != MAGIC2) __builtin_amdgcn_s_sleep(1);
        } while (f != MAGIC2);
    }

    // ---- finalize: fixed-order reduction of 512 packed slots ----
    {
        unsigned long long w0 = __hip_atomic_load(&slots[2 * tid + 0], __ATOMIC_RELAXED, __HIP_MEMORY_SCOPE_AGENT);
        unsigned long long w1 = __hip_atomic_load(&slots[2 * tid + 1], __ATOMIC_RELAXED, __HIP_MEMORY_SCOPE_AGENT);
        float S = __uint_as_float((unsigned)(w0 & 0xffffffffull))
                + __uint_as_float((unsigned)(w1 & 0xffffffffull));
        float C = __uint_as_float((unsigned)(w0 >> 32))
                + __uint_as_float((unsigned)(w1 >> 32));
        #pragma unroll
        for (int off = 32; off > 0; off >>= 1) {
            S += __shfl_down(S, off, 64);
            C += __shfl_down(C, off, 64);
        }
        if ((tid & 63) == 0) { rs[tid >> 6] = S; rc[tid >> 6] = C; }
        __syncthreads();
        if (tid == 0) {
            float SS = rs[0] + rs[1] + rs[2] + rs[3];
            float CC = rc[0] + rc[1] + rc[2] + rc[3];
            out[0] = (CC > 0.0f) ? (SS / CC) : 0.0f;
        }
        // clear my two flags for the next replay (my reads are done)
        __hip_atomic_store(&flags[2 * tid + 0], 0u, __ATOMIC_RELAXED, __HIP_MEMORY_SCOPE_AGENT);
        __hip_atomic_store(&flags[2 * tid + 1], 0u, __ATOMIC_RELAXED, __HIP_MEMORY_SCOPE_AGENT);
    }
}

extern "C" void kernel_launch(void* const* d_in, const int* in_sizes, int n_in,
                              void* d_out, int out_size, void* d_ws, size_t ws_size,
                              hipStream_t stream) {
    const float* y_pred       = (const float*)d_in[0];   // (8,1,512,512) f32
    const int*   point_labels = (const int*)d_in[1];     // (8,20) i32
    const float* point_coords = (const float*)d_in[2];   // (8,20,2) f32
    float*       out          = (float*)d_out;           // scalar f32

    char* w = (char*)d_ws;
    unsigned long long* slots = (unsigned long long*)(w);          // 512 x 8B
    unsigned*           flags = (unsigned*)(w + 4096);             // 512 u32 (8B-aligned)

    pce_kernel<<<NBLOCKS, 256, 0, stream>>>(y_pred, point_labels, point_coords,
                                            slots, flags, out);
}